// Round 1
// baseline (248.105 us; speedup 1.0000x reference)
//
#include <hip/hip_runtime.h>
#include <cstdint>

typedef __attribute__((ext_vector_type(8))) __bf16 bf16x8;
typedef __attribute__((ext_vector_type(4))) float f32x4;
typedef __attribute__((ext_vector_type(8))) short short8;
typedef __attribute__((ext_vector_type(4))) float float4v;

__device__ __forceinline__ unsigned short f2bf(float f) {
    unsigned u = __builtin_bit_cast(unsigned, f);
    u += 0x7fffu + ((u >> 16) & 1u);   // RNE
    return (unsigned short)(u >> 16);
}

__device__ __forceinline__ f32x4 mfma_bf16(bf16x8 a, bf16x8 b, f32x4 c) {
    return __builtin_amdgcn_mfma_f32_16x16x32_bf16(a, b, c, 0, 0, 0);
}

#define GLD16(g, l)                                                                     \
    __builtin_amdgcn_global_load_lds((const __attribute__((address_space(1))) void*)(g), \
                                     (__attribute__((address_space(3))) void*)(l), 16, 0, 0)

// ---------------------------------------------------------------------------
// fp32 -> bf16 conversion, 8 elems/thread, grid sized to cover exactly.
// ---------------------------------------------------------------------------
__global__ void __launch_bounds__(256) cvt_f32_bf16(const float* __restrict__ src,
                                                    unsigned short* __restrict__ dst, int n8) {
    const int stride = gridDim.x * blockDim.x;
    for (int i = blockIdx.x * blockDim.x + threadIdx.x; i < n8; i += stride) {
        const float4v* s = (const float4v*)(src + (size_t)i * 8);
        float4v v0 = s[0], v1 = s[1];
        short8 o;
        o[0] = (short)f2bf(v0[0]); o[1] = (short)f2bf(v0[1]);
        o[2] = (short)f2bf(v0[2]); o[3] = (short)f2bf(v0[3]);
        o[4] = (short)f2bf(v1[0]); o[5] = (short)f2bf(v1[1]);
        o[6] = (short)f2bf(v1[2]); o[7] = (short)f2bf(v1[3]);
        *(short8*)(dst + (size_t)i * 8) = o;
    }
}

// ---------------------------------------------------------------------------
// C[M,N] = A[M,K] * B[N,K]^T + bias[N].  128x128 tile, BK=32, 4 waves (2x2),
// 16x16x32 bf16 MFMA, global_load_lds width-16 staging (m97 structure).
// M,N multiples of 128; K multiple of 32.
// ---------------------------------------------------------------------------
template <bool OUT_BF16>
__global__ void __launch_bounds__(256) gemm_bt(const unsigned short* __restrict__ A,
                                               const unsigned short* __restrict__ B,
                                               const float* __restrict__ bias,
                                               void* __restrict__ C, int M, int N, int K) {
    __shared__ __attribute__((aligned(16))) unsigned short As[128 * 32];
    __shared__ __attribute__((aligned(16))) unsigned short Bs[128 * 32];
    const int tid = threadIdx.x;
    const int w = tid >> 6, lane = tid & 63;
    const int a = lane & 15, g = lane >> 4;
    const int m0 = blockIdx.y * 128, n0 = blockIdx.x * 128;
    const int wr = (w >> 1) * 64, wc = (w & 1) * 64;

    f32x4 acc[4][4];
#pragma unroll
    for (int i = 0; i < 4; i++)
#pragma unroll
        for (int j = 0; j < 4; j++) acc[i][j] = (f32x4)(0.0f);

    // staging: 2 issues of 4096B per tile-half; thread covers row tid/4, col (tid&3)*8
    const int r0 = tid >> 2;
    const int c0 = (tid & 3) * 8;
    const unsigned short* gA0 = A + (size_t)(m0 + r0) * K + c0;
    const unsigned short* gA1 = A + (size_t)(m0 + 64 + r0) * K + c0;
    const unsigned short* gB0 = B + (size_t)(n0 + r0) * K + c0;
    const unsigned short* gB1 = B + (size_t)(n0 + 64 + r0) * K + c0;
    char* ldsA = (char*)As + w * 1024;  // wave-uniform base; HW adds lane*16
    char* ldsB = (char*)Bs + w * 1024;

    for (int k0 = 0; k0 < K; k0 += 32) {
        GLD16(gA0 + k0, ldsA);
        GLD16(gA1 + k0, ldsA + 4096);
        GLD16(gB0 + k0, ldsB);
        GLD16(gB1 + k0, ldsB + 4096);
        __syncthreads();  // drains vmcnt before barrier

        bf16x8 af[4], bfr[4];
#pragma unroll
        for (int i = 0; i < 4; i++) {
            af[i]  = *(const bf16x8*)&As[(wr + i * 16 + a) * 32 + g * 8];
            bfr[i] = *(const bf16x8*)&Bs[(wc + i * 16 + a) * 32 + g * 8];
        }
#pragma unroll
        for (int i = 0; i < 4; i++)
#pragma unroll
            for (int j = 0; j < 4; j++) acc[i][j] = mfma_bf16(af[i], bfr[j], acc[i][j]);
        __syncthreads();
    }

#pragma unroll
    for (int j = 0; j < 4; j++) {
        const int col = n0 + wc + j * 16 + a;
        const float bv = bias[col];
#pragma unroll
        for (int i = 0; i < 4; i++) {
#pragma unroll
            for (int jr = 0; jr < 4; jr++) {
                const int row = m0 + wr + i * 16 + g * 4 + jr;
                float v = acc[i][j][jr] + bv;
                if (OUT_BF16)
                    ((unsigned short*)C)[(size_t)row * N + col] = f2bf(v);
                else
                    ((float*)C)[(size_t)row * N + col] = v;
            }
        }
    }
}

// ---------------------------------------------------------------------------
// Causal flash attention over qkv[B*S, 3*1024] (bf16), heads=16, Dh=64.
// Block: 64 q-rows of one (b,h); 4 waves x 16 q-rows. KT=64 K/V tiles.
// Output: attn_o[B*S, 1024] bf16 (col = h*64 + d).
// ---------------------------------------------------------------------------
__global__ void __launch_bounds__(256) attn_fwd(const unsigned short* __restrict__ qkv,
                                                unsigned short* __restrict__ o) {
    constexpr int SL = 2048, DM = 1024, DH = 64, LD3 = 3072;
    const int qt = blockIdx.x;        // q-tile: 0..31
    const int bh = blockIdx.y;        // 0..31
    const int b = bh >> 4, h = bh & 15;
    const int tid = threadIdx.x;
    const int w = tid >> 6, lane = tid & 63;
    const int a = lane & 15, g = lane >> 4;

    __shared__ __attribute__((aligned(16))) unsigned short Kl[64][72];  // [k][dh]
    __shared__ __attribute__((aligned(16))) unsigned short Vt[64][72];  // [d][k]
    __shared__ __attribute__((aligned(16))) unsigned short Pl[4][16][72];

    const size_t base = (size_t)b * SL * LD3;
    const int qcol = h * DH, kcol = DM + h * DH, vcol = 2 * DM + h * DH;
    const int q0 = qt * 64;

    // Q fragments hoisted to registers: wave w owns q rows [q0+w*16, +16)
    bf16x8 qf[2];
    {
        const unsigned short* qp = qkv + base + (size_t)(q0 + w * 16 + a) * LD3 + qcol + g * 8;
        qf[0] = *(const bf16x8*)qp;
        qf[1] = *(const bf16x8*)(qp + 32);
    }

    f32x4 of[4];
#pragma unroll
    for (int i = 0; i < 4; i++) of[i] = (f32x4)(0.0f);
    float m_i[4], l_i[4];
#pragma unroll
    for (int j = 0; j < 4; j++) { m_i[j] = -1e30f; l_i[j] = 0.0f; }

    const int ntiles = qt + 1;  // causal: only tiles up to the diagonal
    for (int t = 0; t < ntiles; ++t) {
        const int k0 = t * 64;
        __syncthreads();  // prev iteration's LDS reads done before restage
#pragma unroll
        for (int p = 0; p < 2; p++) {
            const int e = p * 2048 + tid * 8;
            const int r = e >> 6, c = e & 63;
            const unsigned short* kp = qkv + base + (size_t)(k0 + r) * LD3 + kcol + c;
            *(short8*)&Kl[r][c] = *(const short8*)kp;
            const unsigned short* vp = qkv + base + (size_t)(k0 + r) * LD3 + vcol + c;
            short8 vv = *(const short8*)vp;
#pragma unroll
            for (int j = 0; j < 8; j++) Vt[c + j][r] = (unsigned short)vv[j];
        }
        __syncthreads();

        // S = Q K^T  (per wave: 16 q-rows x 64 k-cols)
        f32x4 sf[4];
#pragma unroll
        for (int nf = 0; nf < 4; nf++) sf[nf] = (f32x4)(0.0f);
#pragma unroll
        for (int kc = 0; kc < 2; kc++) {
#pragma unroll
            for (int nf = 0; nf < 4; nf++) {
                bf16x8 kb = *(const bf16x8*)&Kl[nf * 16 + a][kc * 32 + g * 8];
                sf[nf] = mfma_bf16(qf[kc], kb, sf[nf]);
            }
        }

        const bool diag = (t == qt);
        float alpha[4];
#pragma unroll
        for (int j = 0; j < 4; j++) {
            const int qg = q0 + w * 16 + g * 4 + j;
            float mx = -1e30f;
#pragma unroll
            for (int nf = 0; nf < 4; nf++) {
                float v = sf[nf][j] * 0.125f;  // 1/sqrt(64)
                if (diag) {
                    const int kg = k0 + nf * 16 + a;
                    v = (kg <= qg) ? v : -1e30f;
                }
                sf[nf][j] = v;
                mx = fmaxf(mx, v);
            }
#pragma unroll
            for (int off = 1; off < 16; off <<= 1) mx = fmaxf(mx, __shfl_xor(mx, off));
            const float mnew = fmaxf(m_i[j], mx);
            float rs = 0.0f;
#pragma unroll
            for (int nf = 0; nf < 4; nf++) {
                const float p = __expf(sf[nf][j] - mnew);
                sf[nf][j] = p;
                rs += p;
            }
#pragma unroll
            for (int off = 1; off < 16; off <<= 1) rs += __shfl_xor(rs, off);
            alpha[j] = __expf(m_i[j] - mnew);
            l_i[j] = l_i[j] * alpha[j] + rs;
            m_i[j] = mnew;
        }
#pragma unroll
        for (int df = 0; df < 4; df++)
#pragma unroll
            for (int j = 0; j < 4; j++) of[df][j] *= alpha[j];

        // P -> LDS (per-wave region), then PV
#pragma unroll
        for (int nf = 0; nf < 4; nf++)
#pragma unroll
            for (int j = 0; j < 4; j++) Pl[w][g * 4 + j][nf * 16 + a] = f2bf(sf[nf][j]);

#pragma unroll
        for (int kc = 0; kc < 2; kc++) {
            bf16x8 pa = *(const bf16x8*)&Pl[w][a][kc * 32 + g * 8];
#pragma unroll
            for (int df = 0; df < 4; df++) {
                bf16x8 vb = *(const bf16x8*)&Vt[df * 16 + a][kc * 32 + g * 8];
                of[df] = mfma_bf16(pa, vb, of[df]);
            }
        }
    }

#pragma unroll
    for (int j = 0; j < 4; j++) {
        const float inv = 1.0f / l_i[j];
        const size_t orow = (size_t)b * SL + q0 + w * 16 + g * 4 + j;
        unsigned short* op = o + orow * DM + h * DH + a;
#pragma unroll
        for (int df = 0; df < 4; df++) op[df * 16] = f2bf(of[df][j] * inv);
    }
}

// ---------------------------------------------------------------------------
extern "C" void kernel_launch(void* const* d_in, const int* in_sizes, int n_in,
                              void* d_out, int out_size, void* d_ws, size_t ws_size,
                              hipStream_t stream) {
    (void)in_sizes; (void)n_in; (void)out_size; (void)ws_size;
    const float* x    = (const float*)d_in[0];
    const float* Wqkv = (const float*)d_in[1];
    const float* bqkv = (const float*)d_in[2];
    const float* Wout = (const float*)d_in[3];
    const float* bout = (const float*)d_in[4];
    float* out = (float*)d_out;

    const int BS = 2, SL = 2048, DM = 1024;
    const int M = BS * SL;   // 4096
    const int N1 = 3 * DM;   // 3072
    const int K = DM;        // 1024

    // workspace layout (bytes): x_bf 8M | wqkv_bf 6M | wout_bf 2M | qkv 24M | attn 8M = 48M
    char* ws = (char*)d_ws;
    unsigned short* x_bf    = (unsigned short*)(ws);
    unsigned short* wqkv_bf = (unsigned short*)(ws + (8u << 20));
    unsigned short* wout_bf = (unsigned short*)(ws + (14u << 20));
    unsigned short* qkv     = (unsigned short*)(ws + (16u << 20));
    unsigned short* attn_o  = (unsigned short*)(ws + (40u << 20));

    cvt_f32_bf16<<<2048, 256, 0, stream>>>(x, x_bf, M * K / 8);
    cvt_f32_bf16<<<1536, 256, 0, stream>>>(Wqkv, wqkv_bf, N1 * K / 8);
    cvt_f32_bf16<<<512, 256, 0, stream>>>(Wout, wout_bf, DM * DM / 8);

    gemm_bt<true><<<dim3(N1 / 128, M / 128), 256, 0, stream>>>(x_bf, wqkv_bf, bqkv, qkv, M, N1, K);

    attn_fwd<<<dim3(SL / 64, BS * 16), 256, 0, stream>>>(qkv, attn_o);

    gemm_bt<false><<<dim3(DM / 128, M / 128), 256, 0, stream>>>(attn_o, wout_bf, bout, out, M, DM, K);
}

// Round 2
// 233.710 us; speedup vs baseline: 1.0616x; 1.0616x over previous
//
#include <hip/hip_runtime.h>
#include <cstdint>

typedef __attribute__((ext_vector_type(8))) __bf16 bf16x8;
typedef __attribute__((ext_vector_type(4))) float f32x4;
typedef __attribute__((ext_vector_type(8))) short short8;
typedef __attribute__((ext_vector_type(4))) float float4v;

__device__ __forceinline__ unsigned short f2bf(float f) {
    unsigned u = __builtin_bit_cast(unsigned, f);
    u += 0x7fffu + ((u >> 16) & 1u);   // RNE
    return (unsigned short)(u >> 16);
}
__device__ __forceinline__ float bf2f(unsigned short s) {
    return __builtin_bit_cast(float, (unsigned)s << 16);
}

__device__ __forceinline__ f32x4 mfma_bf16(bf16x8 a, bf16x8 b, f32x4 c) {
    return __builtin_amdgcn_mfma_f32_16x16x32_bf16(a, b, c, 0, 0, 0);
}

#define GLD16(g, l)                                                                     \
    __builtin_amdgcn_global_load_lds((const __attribute__((address_space(1))) void*)(g), \
                                     (__attribute__((address_space(3))) void*)(l), 16, 0, 0)

// ---------------------------------------------------------------------------
// fp32 -> bf16 conversion, 8 elems/thread.
// ---------------------------------------------------------------------------
__global__ void __launch_bounds__(256) cvt_f32_bf16(const float* __restrict__ src,
                                                    unsigned short* __restrict__ dst, int n8) {
    const int stride = gridDim.x * blockDim.x;
    for (int i = blockIdx.x * blockDim.x + threadIdx.x; i < n8; i += stride) {
        const float4v* s = (const float4v*)(src + (size_t)i * 8);
        float4v v0 = s[0], v1 = s[1];
        short8 o;
        o[0] = (short)f2bf(v0[0]); o[1] = (short)f2bf(v0[1]);
        o[2] = (short)f2bf(v0[2]); o[3] = (short)f2bf(v0[3]);
        o[4] = (short)f2bf(v1[0]); o[5] = (short)f2bf(v1[1]);
        o[6] = (short)f2bf(v1[2]); o[7] = (short)f2bf(v1[3]);
        *(short8*)(dst + (size_t)i * 8) = o;
    }
}

// ---------------------------------------------------------------------------
// C[M,N] = A[M,K] * B[N,K]^T + bias[N].  128x128 tile, BK=32, 4 waves (2x2),
// 16x16x32 bf16 MFMA, global_load_lds width-16 staging (m97 structure).
// ---------------------------------------------------------------------------
template <bool OUT_BF16>
__global__ void __launch_bounds__(256) gemm_bt(const unsigned short* __restrict__ A,
                                               const unsigned short* __restrict__ B,
                                               const float* __restrict__ bias,
                                               void* __restrict__ C, int M, int N, int K) {
    __shared__ __attribute__((aligned(16))) unsigned short As[128 * 32];
    __shared__ __attribute__((aligned(16))) unsigned short Bs[128 * 32];
    const int tid = threadIdx.x;
    const int w = tid >> 6, lane = tid & 63;
    const int a = lane & 15, g = lane >> 4;
    const int m0 = blockIdx.y * 128, n0 = blockIdx.x * 128;
    const int wr = (w >> 1) * 64, wc = (w & 1) * 64;

    f32x4 acc[4][4];
#pragma unroll
    for (int i = 0; i < 4; i++)
#pragma unroll
        for (int j = 0; j < 4; j++) acc[i][j] = (f32x4)(0.0f);

    const int r0 = tid >> 2;
    const int c0 = (tid & 3) * 8;
    const unsigned short* gA0 = A + (size_t)(m0 + r0) * K + c0;
    const unsigned short* gA1 = A + (size_t)(m0 + 64 + r0) * K + c0;
    const unsigned short* gB0 = B + (size_t)(n0 + r0) * K + c0;
    const unsigned short* gB1 = B + (size_t)(n0 + 64 + r0) * K + c0;
    char* ldsA = (char*)As + w * 1024;
    char* ldsB = (char*)Bs + w * 1024;

    for (int k0 = 0; k0 < K; k0 += 32) {
        GLD16(gA0 + k0, ldsA);
        GLD16(gA1 + k0, ldsA + 4096);
        GLD16(gB0 + k0, ldsB);
        GLD16(gB1 + k0, ldsB + 4096);
        __syncthreads();

        bf16x8 af[4], bfr[4];
#pragma unroll
        for (int i = 0; i < 4; i++) {
            af[i]  = *(const bf16x8*)&As[(wr + i * 16 + a) * 32 + g * 8];
            bfr[i] = *(const bf16x8*)&Bs[(wc + i * 16 + a) * 32 + g * 8];
        }
#pragma unroll
        for (int i = 0; i < 4; i++)
#pragma unroll
            for (int j = 0; j < 4; j++) acc[i][j] = mfma_bf16(af[i], bfr[j], acc[i][j]);
        __syncthreads();
    }

#pragma unroll
    for (int j = 0; j < 4; j++) {
        const int col = n0 + wc + j * 16 + a;
        const float bv = bias[col];
#pragma unroll
        for (int i = 0; i < 4; i++) {
#pragma unroll
            for (int jr = 0; jr < 4; jr++) {
                const int row = m0 + wr + i * 16 + g * 4 + jr;
                float v = acc[i][j][jr] + bv;
                if (OUT_BF16)
                    ((unsigned short*)C)[(size_t)row * N + col] = f2bf(v);
                else
                    ((float*)C)[(size_t)row * N + col] = v;
            }
        }
    }
}

// ---------------------------------------------------------------------------
// Causal flash attention over qkv[B*S, 3*1024] (bf16), heads=16, Dh=64.
// Block: 64 q-rows of one (b,h); 4 waves x 16 q-rows.  KVBLK=64.
// v2: reg double-buffered staging (T14), XOR-swizzled K/V LDS (T2),
//     reversed q-tile dispatch for causal load balance, pre-scaled Q.
// ---------------------------------------------------------------------------
__global__ void __launch_bounds__(256) attn_fwd(const unsigned short* __restrict__ qkv,
                                                unsigned short* __restrict__ o) {
    constexpr int SL = 2048, DM = 1024, DH = 64, LD3 = 3072;
    const int qt = (gridDim.x - 1) - blockIdx.x;  // heavy tiles dispatch first
    const int bh = blockIdx.y;
    const int b = bh >> 4, h = bh & 15;
    const int tid = threadIdx.x;
    const int w = tid >> 6, lane = tid & 63;
    const int a = lane & 15, g = lane >> 4;
    const int a3 = a >> 3;

    // swizzled: element (row, col) lives at [row][col ^ (((row>>3)&7)<<3)]
    __shared__ __attribute__((aligned(16))) unsigned short Kl[64][64];  // [k][d]
    __shared__ __attribute__((aligned(16))) unsigned short Vt[64][64];  // [d][k]
    __shared__ __attribute__((aligned(16))) unsigned short Pl[4][16][72];

    const size_t base = (size_t)b * SL * LD3;
    const int qcol = h * DH, kcol = DM + h * DH, vcol = 2 * DM + h * DH;
    const int q0 = qt * 64;

    // staging coords: thread covers rows {r0, r0+32}, cols [ci, ci+8)
    const int r0 = tid >> 3;       // 0..31
    const int cb = tid & 7;        // col block
    const int ci = cb * 8;

    // Q fragments hoisted + pre-scaled by 1/sqrt(Dh)=0.125 (exact pow2 in bf16)
    bf16x8 qf[2];
    {
        const unsigned short* qp = qkv + base + (size_t)(q0 + w * 16 + a) * LD3 + qcol + g * 8;
        short8 qa = *(const short8*)qp;
        short8 qb = *(const short8*)(qp + 32);
        short8 sa, sb;
#pragma unroll
        for (int j = 0; j < 8; j++) {
            sa[j] = (short)f2bf(bf2f((unsigned short)qa[j]) * 0.125f);
            sb[j] = (short)f2bf(bf2f((unsigned short)qb[j]) * 0.125f);
        }
        qf[0] = __builtin_bit_cast(bf16x8, sa);
        qf[1] = __builtin_bit_cast(bf16x8, sb);
    }

    f32x4 of[4];
#pragma unroll
    for (int i = 0; i < 4; i++) of[i] = (f32x4)(0.0f);
    float m_i[4], l_i[4];
#pragma unroll
    for (int j = 0; j < 4; j++) { m_i[j] = -1e30f; l_i[j] = 0.0f; }

    const int ntiles = qt + 1;

    // K/V staging registers (tile in flight)
    short8 kr0, kr1, vr0, vr1;
    const unsigned short* kp0 = qkv + base + (size_t)r0 * LD3 + kcol + ci;
    const unsigned short* vp0 = qkv + base + (size_t)r0 * LD3 + vcol + ci;
    const size_t rowstep = (size_t)32 * LD3;

    // prologue: load + commit tile 0
    {
        const size_t off = 0;
        kr0 = *(const short8*)(kp0 + off);
        kr1 = *(const short8*)(kp0 + off + rowstep);
        vr0 = *(const short8*)(vp0 + off);
        vr1 = *(const short8*)(vp0 + off + rowstep);
        const int sw0 = ci ^ (((r0 >> 3) & 7) << 3);
        const int sw1 = ci ^ ((((r0 + 32) >> 3) & 7) << 3);
        *(short8*)&Kl[r0][sw0] = kr0;
        *(short8*)&Kl[r0 + 32][sw1] = kr1;
        const int vc0 = r0 ^ (cb << 3);
        const int vc1 = (r0 + 32) ^ (cb << 3);
#pragma unroll
        for (int j = 0; j < 8; j++) {
            Vt[ci + j][vc0] = (unsigned short)vr0[j];
            Vt[ci + j][vc1] = (unsigned short)vr1[j];
        }
    }
    __syncthreads();

    for (int t = 0; t < ntiles; ++t) {
        const bool more = (t + 1 < ntiles);
        if (more) {  // issue next tile's loads now; LDS-write after compute
            const size_t off = (size_t)(t + 1) * 64 * LD3;
            kr0 = *(const short8*)(kp0 + off);
            kr1 = *(const short8*)(kp0 + off + rowstep);
            vr0 = *(const short8*)(vp0 + off);
            vr1 = *(const short8*)(vp0 + off + rowstep);
        }

        // ---- S = Q K^T : 16 q-rows x 64 k-cols per wave ----
        f32x4 sf[4];
#pragma unroll
        for (int nf = 0; nf < 4; nf++) sf[nf] = (f32x4)(0.0f);
#pragma unroll
        for (int kc = 0; kc < 2; kc++) {
#pragma unroll
            for (int nf = 0; nf < 4; nf++) {
                const int krow = nf * 16 + a;
                bf16x8 kb = *(const bf16x8*)&Kl[krow][(kc * 32 + g * 8) ^ (((2 * nf + a3) & 7) << 3)];
                sf[nf] = mfma_bf16(qf[kc], kb, sf[nf]);
            }
        }

        // ---- online softmax ----
        const bool diag = (t == qt);
        const int k0 = t * 64;
        float alpha[4];
#pragma unroll
        for (int j = 0; j < 4; j++) {
            const int qg = q0 + w * 16 + g * 4 + j;
            float mx = -1e30f;
#pragma unroll
            for (int nf = 0; nf < 4; nf++) {
                float v = sf[nf][j];
                if (diag) {
                    const int kg = k0 + nf * 16 + a;
                    v = (kg <= qg) ? v : -1e30f;
                }
                sf[nf][j] = v;
                mx = fmaxf(mx, v);
            }
#pragma unroll
            for (int off = 1; off < 16; off <<= 1) mx = fmaxf(mx, __shfl_xor(mx, off));
            const float mnew = fmaxf(m_i[j], mx);
            float rs = 0.0f;
#pragma unroll
            for (int nf = 0; nf < 4; nf++) {
                const float p = __expf(sf[nf][j] - mnew);
                sf[nf][j] = p;
                rs += p;
            }
#pragma unroll
            for (int off = 1; off < 16; off <<= 1) rs += __shfl_xor(rs, off);
            alpha[j] = __expf(m_i[j] - mnew);
            l_i[j] = l_i[j] * alpha[j] + rs;
            m_i[j] = mnew;
        }
#pragma unroll
        for (int df = 0; df < 4; df++)
#pragma unroll
            for (int j = 0; j < 4; j++) of[df][j] *= alpha[j];

        // ---- P -> LDS (per-wave region), then PV ----
#pragma unroll
        for (int nf = 0; nf < 4; nf++)
#pragma unroll
            for (int j = 0; j < 4; j++) Pl[w][g * 4 + j][nf * 16 + a] = f2bf(sf[nf][j]);

#pragma unroll
        for (int kc = 0; kc < 2; kc++) {
            bf16x8 pa = *(const bf16x8*)&Pl[w][a][kc * 32 + g * 8];
#pragma unroll
            for (int df = 0; df < 4; df++) {
                const int drow = df * 16 + a;
                bf16x8 vb = *(const bf16x8*)&Vt[drow][(kc * 32 + g * 8) ^ (((2 * df + a3) & 7) << 3)];
                of[df] = mfma_bf16(pa, vb, of[df]);
            }
        }

        if (more) {
            __syncthreads();  // all waves done reading tile t
            const int sw0 = ci ^ (((r0 >> 3) & 7) << 3);
            const int sw1 = ci ^ ((((r0 + 32) >> 3) & 7) << 3);
            *(short8*)&Kl[r0][sw0] = kr0;
            *(short8*)&Kl[r0 + 32][sw1] = kr1;
            const int vc0 = r0 ^ (cb << 3);
            const int vc1 = (r0 + 32) ^ (cb << 3);
#pragma unroll
            for (int j = 0; j < 8; j++) {
                Vt[ci + j][vc0] = (unsigned short)vr0[j];
                Vt[ci + j][vc1] = (unsigned short)vr1[j];
            }
            __syncthreads();  // staged tile visible
        }
    }

#pragma unroll
    for (int j = 0; j < 4; j++) {
        const float inv = 1.0f / l_i[j];
        const size_t orow = (size_t)b * SL + q0 + w * 16 + g * 4 + j;
        unsigned short* op = o + orow * DM + h * DH + a;
#pragma unroll
        for (int df = 0; df < 4; df++) op[df * 16] = f2bf(of[df][j] * inv);
    }
}

// ---------------------------------------------------------------------------
extern "C" void kernel_launch(void* const* d_in, const int* in_sizes, int n_in,
                              void* d_out, int out_size, void* d_ws, size_t ws_size,
                              hipStream_t stream) {
    (void)in_sizes; (void)n_in; (void)out_size; (void)ws_size;
    const float* x    = (const float*)d_in[0];
    const float* Wqkv = (const float*)d_in[1];
    const float* bqkv = (const float*)d_in[2];
    const float* Wout = (const float*)d_in[3];
    const float* bout = (const float*)d_in[4];
    float* out = (float*)d_out;

    const int BS = 2, SL = 2048, DM = 1024;
    const int M = BS * SL;   // 4096
    const int N1 = 3 * DM;   // 3072
    const int K = DM;        // 1024

    char* ws = (char*)d_ws;
    unsigned short* x_bf    = (unsigned short*)(ws);
    unsigned short* wqkv_bf = (unsigned short*)(ws + (8u << 20));
    unsigned short* wout_bf = (unsigned short*)(ws + (14u << 20));
    unsigned short* qkv     = (unsigned short*)(ws + (16u << 20));
    unsigned short* attn_o  = (unsigned short*)(ws + (40u << 20));

    cvt_f32_bf16<<<2048, 256, 0, stream>>>(x, x_bf, M * K / 8);
    cvt_f32_bf16<<<1536, 256, 0, stream>>>(Wqkv, wqkv_bf, N1 * K / 8);
    cvt_f32_bf16<<<512, 256, 0, stream>>>(Wout, wout_bf, DM * DM / 8);

    gemm_bt<true><<<dim3(N1 / 128, M / 128), 256, 0, stream>>>(x_bf, wqkv_bf, bqkv, qkv, M, N1, K);

    attn_fwd<<<dim3(SL / 64, BS * 16), 256, 0, stream>>>(qkv, attn_o);

    gemm_bt<false><<<dim3(DM / 128, M / 128), 256, 0, stream>>>(attn_o, wout_bf, bout, out, M, DM, K);
}